// Round 5
// baseline (275.971 us; speedup 1.0000x reference)
//
#include <hip/hip_runtime.h>

// B=64, M=16, T=2048, L=64, K=32, N=1985
#define B_ 64
#define M_ 16
#define T_ 2048
#define L_ 64
#define K_ 32
#define N_ (T_ - L_ + 1)   // 1985
#define TN 128             // n-positions per block tile
#define NTH 256            // 16 n-groups (8n) x 16 k-groups (2k)
#define XSTR 212           // 192 data + cumulative skew (max col 211)
#define SHSTR 68           // sh2 row stride (64 + 4 pad)
#define SQSTR 132          // sqw row stride (128 + 4 pad)

// CUMULATIVE column skew: +4 floats per 32-float block (monotone -> injective).
// float4 groups are 4-aligned within a block, never straddle -> stay contiguous.
// Main-loop b128 reads across 16 n-groups -> 2-way bank aliasing (free, m136).
__device__ __forceinline__ int xcol(int j) { return j + 4 * (j >> 5); }

__global__ void init_out_kernel(unsigned* __restrict__ out) {
    int i = blockIdx.x * 256 + threadIdx.x;
    if (i < B_ * K_) out[i] = 0x7F800000u;  // +inf
}

// waves_per_eu(4,4): pin allocator budget to exactly 4 waves/EU (=128 VGPR).
// R4 evidence: with only a min bound the backend squeezed to 64 VGPR (8-wave
// boundary) via spill/remat (WRITE_SIZE 0.5->5.4 MB) -- useless, grid is
// capped at 4 blocks/CU anyway.
__global__ __launch_bounds__(NTH)
__attribute__((amdgpu_waves_per_eu(4, 4)))
void shapelet_kernel(const float* __restrict__ x,
                     const float* __restrict__ shp,
                     const float* __restrict__ pmap,
                     unsigned* __restrict__ out) {
    // LDS: 13568 + 8704 + 8448 + 128 = 30848 B -> 4 blocks/CU (123 KB of 160 KB)
    __shared__ __align__(16) float xs[M_][XSTR];    // x slice, skewed columns
    __shared__ __align__(16) float sh2[K_][SHSTR];  // shapelets [k][l], padded
    __shared__ __align__(16) float sqw[M_][SQSTR];  // sliding sum of x^2
    __shared__ __align__(16) float ss_l[K_];        // sum of s^2 per shapelet

    const int tid = threadIdx.x;
    const int b  = blockIdx.y;
    const int n0 = blockIdx.x * TN;

    // ---- stage x[b,:,n0..n0+191] as float4 groups (zero-fill past T) ----
    const float* xb = x + (size_t)b * (M_ * T_);
    for (int g = tid; g < M_ * 48; g += NTH) {
        int m  = g / 48;
        int j4 = (g - m * 48) * 4;
        int t  = n0 + j4;                       // 4-aligned; T_ is 4-aligned
        float4 v = make_float4(0.f, 0.f, 0.f, 0.f);
        if (t < T_) v = *(const float4*)(xb + m * T_ + t);
        *(float4*)&xs[m][xcol(j4)] = v;
    }
    // ---- stage shapelets sh2[k][l] (row-major copy, float4) ----
    for (int g = tid; g < K_ * 16; g += NTH) {
        int k  = g >> 4;
        int l4 = (g & 15) * 4;
        *(float4*)&sh2[k][l4] = *(const float4*)(shp + k * L_ + l4);
    }
    // ---- ss[k] = sum_l s[k,l]^2 ----
    if (tid < K_) {
        float s = 0.f;
        for (int l = 0; l < L_; ++l) { float v = shp[tid * L_ + l]; s = fmaf(v, v, s); }
        ss_l[tid] = s;
    }
    __syncthreads();

    // ---- sqw[m][j] = sum_{l<64} x^2 sliding window, 8 entries/thread ----
    // Initial 64-sum via 16 b128 reads (R4's scalar version was 8-way conflicted).
    {
        int m  = tid >> 4;
        int j0 = (tid & 15) * 8;
        float s = 0.f;
#pragma unroll
        for (int q = 0; q < 16; ++q) {
            float4 v = *(const float4*)&xs[m][xcol(j0 + q * 4)];
            s = fmaf(v.x, v.x, s); s = fmaf(v.y, v.y, s);
            s = fmaf(v.z, v.z, s); s = fmaf(v.w, v.w, s);
        }
        sqw[m][j0] = s;
#pragma unroll
        for (int d = 1; d < 8; ++d) {
            float a = xs[m][xcol(j0 + d + L_ - 1)];
            float r = xs[m][xcol(j0 + d - 1)];
            s += a * a - r * r;
            sqw[m][j0 + d] = s;
        }
    }
    __syncthreads();

    // ---- per-thread micro-tile: 8 consecutive n x 2 k ----
    const int nig = tid & 15;
    const int kig = tid >> 4;        // 0..15
    const int jb  = nig * 8;
    const int kb  = kig * 2;

    const float ssk0 = ss_l[kb], ssk1 = ss_l[kb + 1];

    float acc[8][2];
#pragma unroll
    for (int i = 0; i < 8; ++i) { acc[i][0] = 0.f; acc[i][1] = 0.f; }

#pragma unroll 1
    for (int m2 = 0; m2 < M_; m2 += 2) {
        float c0[8][2], c1[8][2];
#pragma unroll
        for (int i = 0; i < 8; ++i) {
            c0[i][0] = 0.f; c0[i][1] = 0.f; c1[i][0] = 0.f; c1[i][1] = 0.f;
        }

        // rotating 16-float register windows over xs[m][jb + ...]
        float wv0[16], wv1[16];
        *(float4*)&wv0[0] = *(const float4*)&xs[m2    ][xcol(jb)];
        *(float4*)&wv0[4] = *(const float4*)&xs[m2    ][xcol(jb + 4)];
        *(float4*)&wv1[0] = *(const float4*)&xs[m2 + 1][xcol(jb)];
        *(float4*)&wv1[4] = *(const float4*)&xs[m2 + 1][xcol(jb + 4)];

#pragma unroll 1
        for (int cc = 0; cc < 4; ++cc) {         // rolled: keeps body ~5 KB (I$-safe)
#pragma unroll
            for (int p = 0; p < 4; ++p) {
                const int ch  = cc * 4 + p;
                const int dst = ((p + 2) * 4) & 15;  // slot of chunk ch+2 (cc-invariant)
                *(float4*)&wv0[dst] = *(const float4*)&xs[m2    ][xcol(jb + (ch + 2) * 4)];
                *(float4*)&wv1[dst] = *(const float4*)&xs[m2 + 1][xcol(jb + (ch + 2) * 4)];
                const float4 s0 = *(const float4*)&sh2[kb    ][ch * 4];  // 4 l's of k=kb
                const float4 s1 = *(const float4*)&sh2[kb + 1][ch * 4];
#pragma unroll
                for (int dl = 0; dl < 4; ++dl) {
                    const float sa = ((const float*)&s0)[dl];
                    const float sb = ((const float*)&s1)[dl];
#pragma unroll
                    for (int i = 0; i < 8; ++i) {
                        const int o = (p * 4 + dl + i) & 15;
                        const float xv0 = wv0[o];
                        const float xv1 = wv1[o];
                        c0[i][0] = fmaf(xv0, sa, c0[i][0]);
                        c0[i][1] = fmaf(xv0, sb, c0[i][1]);
                        c1[i][0] = fmaf(xv1, sa, c1[i][0]);
                        c1[i][1] = fmaf(xv1, sb, c1[i][1]);
                    }
                }
            }
        }

        // ---- apply penalty for the two m's ----
#pragma unroll
        for (int mm = 0; mm < 2; ++mm) {
            const int m = m2 + mm;
            float (&c)[8][2] = mm ? c1 : c0;
            float sq[8];
            *(float4*)&sq[0] = *(const float4*)&sqw[m][jb];
            *(float4*)&sq[4] = *(const float4*)&sqw[m][jb + 4];
#pragma unroll
            for (int kk = 0; kk < 2; ++kk) {
                const float* pr = pmap + ((size_t)((kb + kk) * M_ + m)) * N_ + n0 + jb;
                const float ssv = kk ? ssk1 : ssk0;
#pragma unroll
                for (int i = 0; i < 8; ++i) {
                    const bool valid = (n0 + jb + i) < N_;
                    const float p  = valid ? pr[i] : 0.f;
                    // elu(-p)+2: p<0 -> 2-p ; p>=0 -> exp(-p)+1
                    const float pe = (p < 0.f) ? (2.f - p) : (__expf(-p) + 1.f);
                    acc[i][kk] = fmaf(pe, fmaf(-2.f, c[i][kk], sq[i] + ssv), acc[i][kk]);
                }
            }
        }
    }

    // ---- min over 8 n, then over the 16-lane n-group, then one atomicMin ----
#pragma unroll
    for (int kk = 0; kk < 2; ++kk) {
        float lmin = __int_as_float(0x7F800000);
#pragma unroll
        for (int i = 0; i < 8; ++i) {
            if (n0 + jb + i < N_) lmin = fminf(lmin, acc[i][kk]);
        }
        lmin = fminf(lmin, __shfl_xor(lmin, 1));
        lmin = fminf(lmin, __shfl_xor(lmin, 2));
        lmin = fminf(lmin, __shfl_xor(lmin, 4));
        lmin = fminf(lmin, __shfl_xor(lmin, 8));
        if (nig == 0) {
            atomicMin(out + (size_t)b * K_ + kb + kk, __float_as_uint(fmaxf(lmin, 0.f)));
        }
    }
}

extern "C" void kernel_launch(void* const* d_in, const int* in_sizes, int n_in,
                              void* d_out, int out_size, void* d_ws, size_t ws_size,
                              hipStream_t stream) {
    const float* x    = (const float*)d_in[0];   // (B, M, T)
    const float* shp  = (const float*)d_in[1];   // (K, L)
    const float* pmap = (const float*)d_in[2];   // (K, M, N)
    unsigned* out = (unsigned*)d_out;            // (B, K) float bits

    init_out_kernel<<<dim3((B_ * K_ + 255) / 256), dim3(256), 0, stream>>>(out);

    dim3 grid((N_ + TN - 1) / TN, B_);           // 16 x 64 = 1024 blocks, 4/CU
    shapelet_kernel<<<grid, dim3(NTH), 0, stream>>>(x, shp, pmap, out);
}

// Round 6
// 110.568 us; speedup vs baseline: 2.4959x; 2.4959x over previous
//
#include <hip/hip_runtime.h>
#include <hip/hip_bf16.h>

// B=64, M=16, T=2048, L=64, K=32, N=1985
#define B_ 64
#define M_ 16
#define T_ 2048
#define L_ 64
#define K_ 32
#define N_ (T_ - L_ + 1)   // 1985
#define TN 64              // n-positions per block
#define NB 2               // b's per block (pen/pmap amortization)
#define NTH 256            // 4 waves: wave w owns n-subtile [16w,16w+16), both k-tiles
#define XROW 128           // xbuf row elems (127 used, padded)
#define STSTR 72           // st row stride elems (64+8)
#define SQSTR 68           // sqw row stride (64+4)

typedef __attribute__((ext_vector_type(8))) short bf16x8;
typedef __attribute__((ext_vector_type(4))) float f32x4;

__device__ __forceinline__ unsigned short f2bf(float f) {
    __hip_bfloat16 h = __float2bfloat16(f);
    return __builtin_bit_cast(unsigned short, h);
}

// funnel: low 32 of ((hi:lo) >> sh), sh in {0,16}
__device__ __forceinline__ unsigned funnel16(unsigned lo, unsigned hi, unsigned sh) {
    return (unsigned)(((((unsigned long long)hi) << 32) | lo) >> sh);
}

// Extract 16B at byte offset 2*rho from the 32B window {a,b} (aligned b128 pair).
__device__ __forceinline__ bf16x8 extract_frag(uint4 a, uint4 b, unsigned sh, int c2) {
    unsigned t0 = funnel16(a.x, a.y, sh), t1 = funnel16(a.y, a.z, sh);
    unsigned t2 = funnel16(a.z, a.w, sh), t3 = funnel16(a.w, b.x, sh);
    unsigned t4 = funnel16(b.x, b.y, sh), t5 = funnel16(b.y, b.z, sh);
    unsigned t6 = funnel16(b.z, b.w, sh);
    const bool s2 = (c2 & 2), s1 = (c2 & 1);
    unsigned u0 = s2 ? t2 : t0, u1 = s2 ? t3 : t1, u2 = s2 ? t4 : t2;
    unsigned u3 = s2 ? t5 : t3, u4 = s2 ? t6 : t4;
    union { unsigned u[4]; bf16x8 v; } cvt;
    cvt.u[0] = s1 ? u1 : u0; cvt.u[1] = s1 ? u2 : u1;
    cvt.u[2] = s1 ? u3 : u2; cvt.u[3] = s1 ? u4 : u3;
    return cvt.v;
}

__global__ void init_out_kernel(unsigned* __restrict__ out) {
    int i = blockIdx.x * 256 + threadIdx.x;
    if (i < B_ * K_) out[i] = 0x7F800000u;  // +inf
}

__global__ __launch_bounds__(NTH, 2)
void shapelet_mfma_kernel(const float* __restrict__ x,
                          const float* __restrict__ shp,
                          const float* __restrict__ pmap,
                          unsigned* __restrict__ out) {
    // LDS: 8192 + 4608 + 8704 + 128 = 21.6 KB -> 4 blocks/CU easily
    __shared__ __align__(16) unsigned short xbuf[NB][M_][XROW];  // x as bf16 bits
    __shared__ __align__(16) unsigned short st[K_][STSTR];       // shapelets [k][l] bf16
    __shared__ __align__(16) float sqw[NB][M_][SQSTR];           // fp32 sliding sum x^2
    __shared__ float ss_l[K_];                                   // fp32 sum s^2

    const int tid = threadIdx.x;
    const int n0 = blockIdx.x * TN;
    const int b0 = blockIdx.y * NB;
    const bool fast = (n0 + TN < T_);   // false only for last tile (n0=1984)

    // ---- stage x[b0..b0+1][m][n0..n0+126] as bf16 (fast: float4; slow: guarded) ----
    for (int g = tid; g < NB * M_ * 32; g += NTH) {
        const int bi = g >> 9, m = (g >> 5) & 15, j4 = (g & 31) * 4;
        const float* src = x + ((size_t)(b0 + bi) * M_ + m) * T_ + n0 + j4;
        float4 v;
        if (fast) {
            v = *(const float4*)src;
        } else {
            v = make_float4(0.f, 0.f, 0.f, 0.f);
            const int t = n0 + j4;
            if (t     < T_) v.x = src[0];
            if (t + 1 < T_) v.y = src[1];
            if (t + 2 < T_) v.z = src[2];
            if (t + 3 < T_) v.w = src[3];
        }
        ushort4 sv = { f2bf(v.x), f2bf(v.y), f2bf(v.z), f2bf(v.w) };
        *(ushort4*)&xbuf[bi][m][j4] = sv;
    }
    // ---- stage shapelets st[k][l] bf16 ----
    for (int i = tid; i < K_ * 16; i += NTH) {
        const int k = i >> 4, l4 = (i & 15) * 4;
        float4 v = *(const float4*)(shp + k * L_ + l4);
        ushort4 sv = { f2bf(v.x), f2bf(v.y), f2bf(v.z), f2bf(v.w) };
        *(ushort4*)&st[k][l4] = sv;
    }
    // ---- ss[k] fp32 ----
    if (tid < K_) {
        float s = 0.f;
        for (int l = 0; l < L_; ++l) { float v = shp[tid * L_ + l]; s = fmaf(v, v, s); }
        ss_l[tid] = s;
    }
    // ---- sqw fp32 sliding window: 8 threads per (bi,m), 8 n each ----
    {
        const int pm = tid >> 3, th = tid & 7;
        const int bi = pm >> 4, m = pm & 15, j0 = th * 8;
        const float* xr = x + ((size_t)(b0 + bi) * M_ + m) * T_ + n0;
        float s = 0.f;
        if (fast) {
#pragma unroll
            for (int qd = 0; qd < 16; ++qd) {
                float4 v = *(const float4*)(xr + j0 + qd * 4);
                s = fmaf(v.x, v.x, s); s = fmaf(v.y, v.y, s);
                s = fmaf(v.z, v.z, s); s = fmaf(v.w, v.w, s);
            }
            sqw[bi][m][j0] = s;
#pragma unroll
            for (int d = 1; d < 8; ++d) {
                float a = xr[j0 + d + L_ - 1], r = xr[j0 + d - 1];
                s += a * a - r * r;
                sqw[bi][m][j0 + d] = s;
            }
        } else {
            for (int l = 0; l < L_; ++l) {
                float v = (n0 + j0 + l < T_) ? xr[j0 + l] : 0.f;
                s = fmaf(v, v, s);
            }
            sqw[bi][m][j0] = s;
            for (int d = 1; d < 8; ++d) {
                float a = (n0 + j0 + d + L_ - 1 < T_) ? xr[j0 + d + L_ - 1] : 0.f;
                float r = (n0 + j0 + d - 1 < T_) ? xr[j0 + d - 1] : 0.f;
                s += a * a - r * r;
                sqw[bi][m][j0 + d] = s;
            }
        }
    }
    __syncthreads();

    // ---- per-lane MFMA coordinates ----
    const int lane = tid & 63;
    const int w  = tid >> 6;       // wave -> n-subtile [16w, 16w+16)
    const int rl = lane & 15;      // A-row (n within subtile) / B-col (k within tile)
    const int q  = lane >> 4;      // quad
    const int rho = rl & 7, r8 = rl >> 3;
    const unsigned sh = (unsigned)((rho & 1) * 16);
    const int c2 = rho >> 1;
    const int Gb = 2 * w + q + r8; // aligned 16B-group base for A windows

    // b_frags (registers, whole kernel): st[16t+rl][8q+32h .. +7]
    bf16x8 bfr[2][2];
#pragma unroll
    for (int t = 0; t < 2; ++t)
#pragma unroll
        for (int h = 0; h < 2; ++h)
            bfr[t][h] = *(const bf16x8*)&st[16 * t + rl][8 * q + 32 * h];

    const float ssk0 = ss_l[rl], ssk1 = ss_l[16 + rl];

    f32x4 wd[NB][2];
#pragma unroll
    for (int bi = 0; bi < NB; ++bi) { wd[bi][0] = (f32x4)0.f; wd[bi][1] = (f32x4)0.f; }

    const int nrow = n0 + 16 * w + 4 * q;   // lane's 4 output rows: nrow + reg
    const f32x4 zero = (f32x4)0.f;

#pragma unroll 1
    for (int m = 0; m < M_; ++m) {
        // ---- penalty for this m (shared across bi): pmap[k][m][nrow..+3] ----
        float4 p0, p1;
        const float* pr0 = pmap + ((size_t)(rl * M_ + m)) * N_ + nrow;
        const float* pr1 = pmap + ((size_t)((16 + rl) * M_ + m)) * N_ + nrow;
        if (fast) {
            p0 = *(const float4*)pr0;
            p1 = *(const float4*)pr1;
        } else {
            p0 = make_float4(0.f, 0.f, 0.f, 0.f);
            p1 = make_float4(0.f, 0.f, 0.f, 0.f);
            if (nrow     < N_) { p0.x = pr0[0]; p1.x = pr1[0]; }
            if (nrow + 1 < N_) { p0.y = pr0[1]; p1.y = pr1[1]; }
            if (nrow + 2 < N_) { p0.z = pr0[2]; p1.z = pr1[2]; }
            if (nrow + 3 < N_) { p0.w = pr0[3]; p1.w = pr1[3]; }
        }
        float pen0[4], pen1[4];
        pen0[0] = (p0.x < 0.f) ? (2.f - p0.x) : (__expf(-p0.x) + 1.f);
        pen0[1] = (p0.y < 0.f) ? (2.f - p0.y) : (__expf(-p0.y) + 1.f);
        pen0[2] = (p0.z < 0.f) ? (2.f - p0.z) : (__expf(-p0.z) + 1.f);
        pen0[3] = (p0.w < 0.f) ? (2.f - p0.w) : (__expf(-p0.w) + 1.f);
        pen1[0] = (p1.x < 0.f) ? (2.f - p1.x) : (__expf(-p1.x) + 1.f);
        pen1[1] = (p1.y < 0.f) ? (2.f - p1.y) : (__expf(-p1.y) + 1.f);
        pen1[2] = (p1.z < 0.f) ? (2.f - p1.z) : (__expf(-p1.z) + 1.f);
        pen1[3] = (p1.w < 0.f) ? (2.f - p1.w) : (__expf(-p1.w) + 1.f);

#pragma unroll
        for (int bi = 0; bi < NB; ++bi) {
            const uint4* px = (const uint4*)&xbuf[bi][m][0];
            // A windows: aligned b128 pairs, funnel-extract at byte 2*rho
            uint4 w0 = px[Gb],     w1 = px[Gb + 1];  // h=0
            uint4 w2 = px[Gb + 4], w3 = px[Gb + 5];  // h=1
            bf16x8 a0 = extract_frag(w0, w1, sh, c2);
            bf16x8 a1 = extract_frag(w2, w3, sh, c2);

            f32x4 corr0 = __builtin_amdgcn_mfma_f32_16x16x32_bf16(a0, bfr[0][0], zero, 0, 0, 0);
            corr0       = __builtin_amdgcn_mfma_f32_16x16x32_bf16(a1, bfr[0][1], corr0, 0, 0, 0);
            f32x4 corr1 = __builtin_amdgcn_mfma_f32_16x16x32_bf16(a0, bfr[1][0], zero, 0, 0, 0);
            corr1       = __builtin_amdgcn_mfma_f32_16x16x32_bf16(a1, bfr[1][1], corr1, 0, 0, 0);

            f32x4 sq = *(const f32x4*)&sqw[bi][m][16 * w + 4 * q];
#pragma unroll
            for (int r = 0; r < 4; ++r) {
                float t0v = fmaf(-2.f, corr0[r], sq[r] + ssk0);
                wd[bi][0][r] = fmaf(pen0[r], t0v, wd[bi][0][r]);
                float t1v = fmaf(-2.f, corr1[r], sq[r] + ssk1);
                wd[bi][1][r] = fmaf(pen1[r], t1v, wd[bi][1][r]);
            }
        }
    }

    // ---- min over lane's 4 rows -> across quads -> atomicMin per (b,k) ----
#pragma unroll
    for (int bi = 0; bi < NB; ++bi) {
#pragma unroll
        for (int t = 0; t < 2; ++t) {
            float lmin = __int_as_float(0x7F800000);
#pragma unroll
            for (int r = 0; r < 4; ++r) {
                if (nrow + r < N_) lmin = fminf(lmin, wd[bi][t][r]);
            }
            lmin = fminf(lmin, __shfl_xor(lmin, 16));
            lmin = fminf(lmin, __shfl_xor(lmin, 32));
            if (q == 0) {
                atomicMin(out + (size_t)(b0 + bi) * K_ + 16 * t + rl,
                          __float_as_uint(fmaxf(lmin, 0.f)));
            }
        }
    }
}

extern "C" void kernel_launch(void* const* d_in, const int* in_sizes, int n_in,
                              void* d_out, int out_size, void* d_ws, size_t ws_size,
                              hipStream_t stream) {
    const float* x    = (const float*)d_in[0];   // (B, M, T)
    const float* shp  = (const float*)d_in[1];   // (K, L)
    const float* pmap = (const float*)d_in[2];   // (K, M, N)
    unsigned* out = (unsigned*)d_out;            // (B, K) float bits

    init_out_kernel<<<dim3((B_ * K_ + 255) / 256), dim3(256), 0, stream>>>(out);

    dim3 grid((N_ + TN - 1) / TN, B_ / NB);      // 32 x 32 = 1024 blocks, 4/CU
    shapelet_mfma_kernel<<<grid, dim3(NTH), 0, stream>>>(x, shp, pmap, out);
}

// Round 7
// 105.958 us; speedup vs baseline: 2.6045x; 1.0435x over previous
//
#include <hip/hip_runtime.h>
#include <hip/hip_bf16.h>

// B=64, M=16, T=2048, L=64, K=32, N=1985
#define B_ 64
#define M_ 16
#define T_ 2048
#define L_ 64
#define K_ 32
#define N_ (T_ - L_ + 1)   // 1985
#define KMN (K_ * M_ * N_) // 1,016,320 (= 4 * 254,080 exactly)
#define TN 64              // n-positions per block
#define NTH 256            // 4 waves: wave w owns n-subtile [16w,16w+16), both k-tiles
#define XROW 128           // xbuf row elems (127 used, padded)
#define STSTR 72           // st row stride elems (64+8)
#define SQSTR 68           // sqw row stride (64+4)

typedef __attribute__((ext_vector_type(8))) short bf16x8;
typedef __attribute__((ext_vector_type(4))) float f32x4;

__device__ __forceinline__ unsigned short f2bf(float f) {
    __hip_bfloat16 h = __float2bfloat16(f);
    return __builtin_bit_cast(unsigned short, h);
}

// funnel: low 32 of ((hi:lo) >> sh), sh in {0,16} -> v_alignbit_b32
__device__ __forceinline__ unsigned funnel16(unsigned lo, unsigned hi, unsigned sh) {
    return (unsigned)(((((unsigned long long)hi) << 32) | lo) >> sh);
}

// Extract 16B at byte offset 2*rho from the 32B window {a,b} (aligned b128 pair).
__device__ __forceinline__ bf16x8 extract_frag(uint4 a, uint4 b, unsigned sh, int c2) {
    unsigned t0 = funnel16(a.x, a.y, sh), t1 = funnel16(a.y, a.z, sh);
    unsigned t2 = funnel16(a.z, a.w, sh), t3 = funnel16(a.w, b.x, sh);
    unsigned t4 = funnel16(b.x, b.y, sh), t5 = funnel16(b.y, b.z, sh);
    unsigned t6 = funnel16(b.z, b.w, sh);
    const bool s2 = (c2 & 2), s1 = (c2 & 1);
    unsigned u0 = s2 ? t2 : t0, u1 = s2 ? t3 : t1, u2 = s2 ? t4 : t2;
    unsigned u3 = s2 ? t5 : t3, u4 = s2 ? t6 : t4;
    union { unsigned u[4]; bf16x8 v; } cvt;
    cvt.u[0] = s1 ? u1 : u0; cvt.u[1] = s1 ? u2 : u1;
    cvt.u[2] = s1 ? u3 : u2; cvt.u[3] = s1 ? u4 : u3;
    return cvt.v;
}

// pen[i] = elu(-pmap[i]) + 2, flat over K*M*N (exact multiple of 4).
// Also initializes out[] to +inf (folds the old init kernel away).
__global__ void pen_init_kernel(const float* __restrict__ pmap,
                                float* __restrict__ pen,
                                unsigned* __restrict__ out) {
    const int gid = blockIdx.x * 256 + threadIdx.x;
    if (gid < B_ * K_) out[gid] = 0x7F800000u;  // +inf
    if (gid < KMN / 4) {
        const int i4 = gid * 4;
        float4 p = *(const float4*)(pmap + i4);
        float4 r;
        r.x = (p.x < 0.f) ? (2.f - p.x) : (__expf(-p.x) + 1.f);
        r.y = (p.y < 0.f) ? (2.f - p.y) : (__expf(-p.y) + 1.f);
        r.z = (p.z < 0.f) ? (2.f - p.z) : (__expf(-p.z) + 1.f);
        r.w = (p.w < 0.f) ? (2.f - p.w) : (__expf(-p.w) + 1.f);
        *(float4*)(pen + i4) = r;
    }
}

__global__ __launch_bounds__(NTH, 2)
void shapelet_mfma_kernel(const float* __restrict__ x,
                          const float* __restrict__ shp,
                          const float* __restrict__ pen,
                          unsigned* __restrict__ out) {
    // LDS: 4096 + 4608 + 4352 + 128 = 13.2 KB -> >=8 blocks/CU (grid-limited)
    __shared__ __align__(16) unsigned short xbuf[M_][XROW];  // x as bf16 bits
    __shared__ __align__(16) unsigned short st[K_][STSTR];   // shapelets [k][l] bf16
    __shared__ __align__(16) float sqw[M_][SQSTR];           // fp32 sliding sum x^2
    __shared__ float ss_l[K_];                               // fp32 sum s^2

    const int tid = threadIdx.x;
    const int n0 = blockIdx.x * TN;
    const int b  = blockIdx.y;
    const bool fast = (n0 + TN < T_);   // false only for last tile (n0=1984)

    // ---- stage x[b][m][n0..n0+127] as bf16 (fast: float4; slow: guarded) ----
    const float* xb = x + ((size_t)b * M_) * T_ + n0;
    for (int g = tid; g < M_ * 32; g += NTH) {
        const int m = g >> 5, j4 = (g & 31) * 4;
        const float* src = xb + m * T_ + j4;
        float4 v;
        if (fast) {
            v = *(const float4*)src;
        } else {
            v = make_float4(0.f, 0.f, 0.f, 0.f);
            const int t = n0 + j4;
            if (t     < T_) v.x = src[0];
            if (t + 1 < T_) v.y = src[1];
            if (t + 2 < T_) v.z = src[2];
            if (t + 3 < T_) v.w = src[3];
        }
        ushort4 sv = { f2bf(v.x), f2bf(v.y), f2bf(v.z), f2bf(v.w) };
        *(ushort4*)&xbuf[m][j4] = sv;
    }
    // ---- stage shapelets st[k][l] bf16 ----
    for (int i = tid; i < K_ * 16; i += NTH) {
        const int k = i >> 4, l4 = (i & 15) * 4;
        float4 v = *(const float4*)(shp + k * L_ + l4);
        ushort4 sv = { f2bf(v.x), f2bf(v.y), f2bf(v.z), f2bf(v.w) };
        *(ushort4*)&st[k][l4] = sv;
    }
    // ---- ss[k] fp32 ----
    if (tid < K_) {
        float s = 0.f;
        for (int l = 0; l < L_; ++l) { float v = shp[tid * L_ + l]; s = fmaf(v, v, s); }
        ss_l[tid] = s;
    }
    // ---- sqw fp32 sliding window: 8 threads per m, 8 n each (threads 0..127) ----
    if (tid < M_ * 8) {
        const int m = tid >> 3, j0 = (tid & 7) * 8;
        const float* xr = x + ((size_t)b * M_ + m) * T_ + n0;
        float s = 0.f;
        if (fast) {
#pragma unroll
            for (int qd = 0; qd < 16; ++qd) {
                float4 v = *(const float4*)(xr + j0 + qd * 4);
                s = fmaf(v.x, v.x, s); s = fmaf(v.y, v.y, s);
                s = fmaf(v.z, v.z, s); s = fmaf(v.w, v.w, s);
            }
            sqw[m][j0] = s;
#pragma unroll
            for (int d = 1; d < 8; ++d) {
                float a = xr[j0 + d + L_ - 1], r = xr[j0 + d - 1];
                s += a * a - r * r;
                sqw[m][j0 + d] = s;
            }
        } else {
            for (int l = 0; l < L_; ++l) {
                float v = (n0 + j0 + l < T_) ? xr[j0 + l] : 0.f;
                s = fmaf(v, v, s);
            }
            sqw[m][j0] = s;
            for (int d = 1; d < 8; ++d) {
                float a = (n0 + j0 + d + L_ - 1 < T_) ? xr[j0 + d + L_ - 1] : 0.f;
                float r = (n0 + j0 + d - 1 < T_) ? xr[j0 + d - 1] : 0.f;
                s += a * a - r * r;
                sqw[m][j0 + d] = s;
            }
        }
    }
    __syncthreads();

    // ---- per-lane MFMA coordinates ----
    const int lane = tid & 63;
    const int w  = tid >> 6;       // wave -> n-subtile [16w, 16w+16)
    const int rl = lane & 15;      // A-row (n within subtile) / B-col (k within tile)
    const int q  = lane >> 4;      // quad
    const int rho = rl & 7, r8 = rl >> 3;
    const unsigned sh = (unsigned)((rho & 1) * 16);
    const int c2 = rho >> 1;
    const int Gb = 2 * w + q + r8; // aligned 16B-group base for A windows

    // b_frags (registers, whole kernel): st[16t+rl][8q+32h .. +7]
    bf16x8 bfr[2][2];
#pragma unroll
    for (int t = 0; t < 2; ++t)
#pragma unroll
        for (int h = 0; h < 2; ++h)
            bfr[t][h] = *(const bf16x8*)&st[16 * t + rl][8 * q + 32 * h];

    const float ssk0 = ss_l[rl], ssk1 = ss_l[16 + rl];

    f32x4 wd0 = (f32x4)0.f, wd1 = (f32x4)0.f;
    const int nrow = n0 + 16 * w + 4 * q;   // lane's 4 output rows: nrow + reg
    const f32x4 zero = (f32x4)0.f;

#pragma unroll 2
    for (int m = 0; m < M_; ++m) {
        // ---- penalty for this m: precomputed pen[k][m][nrow..+3] ----
        float4 p0, p1;
        const float* pr0 = pen + ((size_t)(rl * M_ + m)) * N_ + nrow;
        const float* pr1 = pen + ((size_t)((16 + rl) * M_ + m)) * N_ + nrow;
        if (fast) {
            p0 = *(const float4*)pr0;
            p1 = *(const float4*)pr1;
        } else {
            p0 = make_float4(2.f, 2.f, 2.f, 2.f);   // masked at min; any finite value
            p1 = make_float4(2.f, 2.f, 2.f, 2.f);
            if (nrow     < N_) { p0.x = pr0[0]; p1.x = pr1[0]; }
            if (nrow + 1 < N_) { p0.y = pr0[1]; p1.y = pr1[1]; }
            if (nrow + 2 < N_) { p0.z = pr0[2]; p1.z = pr1[2]; }
            if (nrow + 3 < N_) { p0.w = pr0[3]; p1.w = pr1[3]; }
        }

        const uint4* px = (const uint4*)&xbuf[m][0];
        // A windows: aligned b128 pairs, funnel-extract at byte 2*rho
        uint4 w0 = px[Gb],     w1 = px[Gb + 1];  // h=0
        uint4 w2 = px[Gb + 4], w3 = px[Gb + 5];  // h=1
        bf16x8 a0 = extract_frag(w0, w1, sh, c2);
        bf16x8 a1 = extract_frag(w2, w3, sh, c2);

        f32x4 corr0 = __builtin_amdgcn_mfma_f32_16x16x32_bf16(a0, bfr[0][0], zero, 0, 0, 0);
        corr0       = __builtin_amdgcn_mfma_f32_16x16x32_bf16(a1, bfr[0][1], corr0, 0, 0, 0);
        f32x4 corr1 = __builtin_amdgcn_mfma_f32_16x16x32_bf16(a0, bfr[1][0], zero, 0, 0, 0);
        corr1       = __builtin_amdgcn_mfma_f32_16x16x32_bf16(a1, bfr[1][1], corr1, 0, 0, 0);

        f32x4 sq = *(const f32x4*)&sqw[m][16 * w + 4 * q];
        const float pe0[4] = { p0.x, p0.y, p0.z, p0.w };
        const float pe1[4] = { p1.x, p1.y, p1.z, p1.w };
#pragma unroll
        for (int r = 0; r < 4; ++r) {
            float t0v = fmaf(-2.f, corr0[r], sq[r] + ssk0);
            wd0[r] = fmaf(pe0[r], t0v, wd0[r]);
            float t1v = fmaf(-2.f, corr1[r], sq[r] + ssk1);
            wd1[r] = fmaf(pe1[r], t1v, wd1[r]);
        }
    }

    // ---- min over lane's 4 rows -> across quads -> atomicMin per (b,k) ----
#pragma unroll
    for (int t = 0; t < 2; ++t) {
        float lmin = __int_as_float(0x7F800000);
        const f32x4& wdv = t ? wd1 : wd0;
#pragma unroll
        for (int r = 0; r < 4; ++r) {
            if (nrow + r < N_) lmin = fminf(lmin, wdv[r]);
        }
        lmin = fminf(lmin, __shfl_xor(lmin, 16));
        lmin = fminf(lmin, __shfl_xor(lmin, 32));
        if (q == 0) {
            atomicMin(out + (size_t)b * K_ + 16 * t + rl,
                      __float_as_uint(fmaxf(lmin, 0.f)));
        }
    }
}

extern "C" void kernel_launch(void* const* d_in, const int* in_sizes, int n_in,
                              void* d_out, int out_size, void* d_ws, size_t ws_size,
                              hipStream_t stream) {
    const float* x    = (const float*)d_in[0];   // (B, M, T)
    const float* shp  = (const float*)d_in[1];   // (K, L)
    const float* pmap = (const float*)d_in[2];   // (K, M, N)
    unsigned* out = (unsigned*)d_out;            // (B, K) float bits
    float* pen = (float*)d_ws;                   // (K, M, N) elu(-pmap)+2, 3.9 MB

    pen_init_kernel<<<dim3((KMN / 4 + 255) / 256), dim3(256), 0, stream>>>(pmap, pen, out);

    dim3 grid((N_ + TN - 1) / TN, B_);           // 32 x 64 = 2048 blocks, 8/CU
    shapelet_mfma_kernel<<<grid, dim3(NTH), 0, stream>>>(x, shp, pen, out);
}